// Round 4
// baseline (106.219 us; speedup 1.0000x reference)
//
#include <hip/hip_runtime.h>

typedef __attribute__((ext_vector_type(8))) short short8;
typedef __attribute__((ext_vector_type(16))) float f32x16;
typedef __attribute__((ext_vector_type(4))) float f32x4;
typedef __attribute__((ext_vector_type(2))) float f32x2;
typedef __attribute__((ext_vector_type(2))) unsigned int uint2v;

#define HW 1026
#define CH_STRIDE (HW * HW)          /* 1052676 */
#define TH 8                         /* output rows per block    */
#define TW 32                        /* output cols per block    */
#define LDS_ROWS 10                  /* TH + 2 halo              */
#define ROW_BYTES 1088               /* 34 px * 16ch * 2B        */
#define UNITS_PER_C4 (LDS_ROWS * 17) /* 170 units of 4ch x 2px   */
#define NUNITS (4 * UNITS_PER_C4)    /* 680 */

__device__ __forceinline__ unsigned short f2bf(float f) {
    unsigned int u = __builtin_bit_cast(unsigned int, f);
    u += 0x7fffu + ((u >> 16) & 1u);
    return (unsigned short)(u >> 16);
}

__global__ __launch_bounds__(256, 4)
void gck3x3_mfma_kernel(const float* __restrict__ x,
                        const float* __restrict__ kern,
                        float* __restrict__ out) {
    __shared__ __attribute__((aligned(16))) unsigned char s_x[LDS_ROWS * ROW_BYTES];

    const int tid  = threadIdx.x;
    const int lane = tid & 63;
    const int wv   = tid >> 6;      // 0..3
    const int n    = lane & 31;     // pixel (A-row) / outch (B-col & store)
    const int hi   = lane >> 5;     // k-group: channels 8*hi..8*hi+7

    // XCD-aware bijective swizzle: 4096 = 8 * 512; each XCD gets 16
    // consecutive tile-rows (vertical halo sharing inside one L2)
    const int bid = blockIdx.x;
    const int swz = (bid & 7) * 512 + (bid >> 3);
    const int h0  = (swz >> 5) * TH;   // 0..1016
    const int w0  = (swz & 31) * TW;   // 0..992

    // ---- stage issue: 4ch x 2px units, f32x2 (8B-aligned always) ----
    f32x2 vals[3][4];
    #pragma unroll
    for (int k = 0; k < 3; ++k) {
        const int idx = tid + k * 256;
        if (idx < NUNITS) {
            const int c4  = idx / UNITS_PER_C4;
            const int rem = idx - c4 * UNITS_PER_C4;
            const int row = rem / 17;
            const int u   = rem - row * 17;
            const float* base = x + (4 * c4) * CH_STRIDE + (h0 + row) * HW + (w0 + 2 * u);
            #pragma unroll
            for (int j = 0; j < 4; ++j)
                vals[k][j] = *(const f32x2*)(base + j * CH_STRIDE);
        }
    }

    // ---- weight fragments (B operand now): W[o=n][c=8hi+j][r][s], L2-resident ----
    short8 af[3][3];
    #pragma unroll
    for (int r = 0; r < 3; ++r) {
        #pragma unroll
        for (int s = 0; s < 3; ++s) {
            short8 v;
            #pragma unroll
            for (int j = 0; j < 8; ++j)
                v[j] = (short)f2bf(kern[n * 144 + (8 * hi + j) * 9 + r * 3 + s]);
            af[r][s] = v;
        }
    }

    // ---- stage write: convert + transpose to LDS [row][px][16ch], XOR-swizzled ----
    #pragma unroll
    for (int k = 0; k < 3; ++k) {
        const int idx = tid + k * 256;
        if (idx < NUNITS) {
            const int c4  = idx / UNITS_PER_C4;
            const int rem = idx - c4 * UNITS_PER_C4;
            const int row = rem / 17;
            const int u   = rem - row * 17;
            #pragma unroll
            for (int p = 0; p < 2; ++p) {
                const int pp = 2 * u + p;
                const unsigned int lo  = (unsigned int)f2bf(vals[k][0][p]) |
                                         ((unsigned int)f2bf(vals[k][1][p]) << 16);
                const unsigned int hi2 = (unsigned int)f2bf(vals[k][2][p]) |
                                         ((unsigned int)f2bf(vals[k][3][p]) << 16);
                const int s16 = ((c4 >> 1) ^ (pp >> 2) ^ (pp >> 3)) & 1;
                const int off = row * ROW_BYTES + pp * 32 + s16 * 16 + (c4 & 1) * 8;
                uint2v t; t.x = lo; t.y = hi2;
                *(uint2v*)(s_x + off) = t;
            }
        }
    }
    __syncthreads();

    // ---- compute: A = x-frag (M=pixel), B = weights (N=outch) ----
    // D layout: col(lane&31)=outch, row(q)= (q&3)+8*(q>>2)+4*hi = pixel
    // -> lane owns ONE outch, 4 runs of 4 consecutive pixels -> dwordx4 stores
    #pragma unroll
    for (int t = 0; t < 2; ++t) {
        const int baserow = wv * 2 + t;
        f32x16 acc;
        #pragma unroll
        for (int q = 0; q < 16; ++q) acc[q] = 0.0f;

        #pragma unroll
        for (int r = 0; r < 3; ++r) {
            #pragma unroll
            for (int s = 0; s < 3; ++s) {
                const int w   = n + s;
                const int s16 = (hi ^ (w >> 2) ^ (w >> 3)) & 1;
                const int off = (baserow + r) * ROW_BYTES + w * 32 + s16 * 16;
                const short8 xfr = *(const short8*)(s_x + off);   // ds_read_b128
                acc = __builtin_amdgcn_mfma_f32_32x32x16_bf16(xfr, af[r][s], acc, 0, 0, 0);
            }
        }

        const int h = h0 + baserow;
        float* obase = out + (n << 20) + (h << 10) + w0 + 4 * hi;
        #pragma unroll
        for (int g = 0; g < 4; ++g) {
            f32x4 v;
            v[0] = acc[4 * g + 0]; v[1] = acc[4 * g + 1];
            v[2] = acc[4 * g + 2]; v[3] = acc[4 * g + 3];
            __builtin_nontemporal_store(v, (f32x4*)(obase + 8 * g));
        }
    }
}

extern "C" void kernel_launch(void* const* d_in, const int* in_sizes, int n_in,
                              void* d_out, int out_size, void* d_ws, size_t ws_size,
                              hipStream_t stream) {
    (void)in_sizes; (void)n_in; (void)d_ws; (void)ws_size; (void)out_size;
    const float* x    = (const float*)d_in[0];
    const float* kern = (const float*)d_in[1];
    float*       out  = (float*)d_out;
    gck3x3_mfma_kernel<<<4096, 256, 0, stream>>>(x, kern, out);
}

// Round 5
// 54.483 us; speedup vs baseline: 1.9496x; 1.9496x over previous
//
#include <hip/hip_runtime.h>

typedef __attribute__((ext_vector_type(8))) short short8;
typedef __attribute__((ext_vector_type(16))) float f32x16;
typedef __attribute__((ext_vector_type(2))) float f32x2;
typedef __attribute__((ext_vector_type(2))) unsigned int uint2v;

#define HW 1026
#define CH_STRIDE (HW * HW)          /* 1052676 */
#define ROW_BYTES 1088               /* 34 px * 16ch * 2B */
#define LDS_BYTES (4 * ROW_BYTES)    /* 4 input rows = 4352 B */
#define UNITS_PER_C4 (4 * 17)        /* 68 units (4ch x 2px) per channel-quad */
#define NUNITS (4 * UNITS_PER_C4)    /* 272 */

__device__ __forceinline__ unsigned short f2bf(float f) {
    unsigned int u = __builtin_bit_cast(unsigned int, f);
    u += 0x7fffu + ((u >> 16) & 1u);
    return (unsigned short)(u >> 16);
}

__global__ __launch_bounds__(64, 4)
void gck3x3_mfma_kernel(const float* __restrict__ x,
                        const float* __restrict__ kern,
                        float* __restrict__ out) {
    // one wave per block: private LDS, NO __syncthreads anywhere
    __shared__ __attribute__((aligned(16))) unsigned char s_x[LDS_BYTES];

    const int lane = threadIdx.x;   // 0..63
    const int n    = lane & 31;     // pixel column (store/N) / outch (A-frag row)
    const int hi   = lane >> 5;     // k half: channels 8*hi..8*hi+7

    // XCD-aware bijective swizzle: 16384 = 8 * 2048
    const int bid = blockIdx.x;
    const int swz = (bid & 7) * 2048 + (bid >> 3);
    const int h0  = (swz >> 5) * 2;    // output row pair: 0..1022
    const int w0  = (swz & 31) * 32;   // 0..992

    // ---- issue all global loads: 272 units of 4ch x 2px, f32x2 (8B aligned) ----
    f32x2 vals[5][4];
    #pragma unroll
    for (int k = 0; k < 5; ++k) {
        const int idx = lane + k * 64;
        if (idx < NUNITS) {
            const int c4  = idx / UNITS_PER_C4;
            const int rem = idx - c4 * UNITS_PER_C4;
            const int row = rem / 17;
            const int u   = rem - row * 17;
            const float* base = x + (4 * c4) * CH_STRIDE + (h0 + row) * HW + (w0 + 2 * u);
            #pragma unroll
            for (int j = 0; j < 4; ++j)
                vals[k][j] = *(const f32x2*)(base + j * CH_STRIDE);
        }
    }

    // ---- weight A-fragments: W[o=n][c=8*hi+j][r][s] (L2-resident 18 KB) ----
    short8 af[3][3];
    #pragma unroll
    for (int r = 0; r < 3; ++r) {
        #pragma unroll
        for (int s = 0; s < 3; ++s) {
            short8 v;
            #pragma unroll
            for (int j = 0; j < 8; ++j)
                v[j] = (short)f2bf(kern[n * 144 + (8 * hi + j) * 9 + r * 3 + s]);
            af[r][s] = v;
        }
    }

    // ---- convert + transpose into LDS [row][px][16ch] bf16, XOR-swizzled ----
    #pragma unroll
    for (int k = 0; k < 5; ++k) {
        const int idx = lane + k * 64;
        if (idx < NUNITS) {
            const int c4  = idx / UNITS_PER_C4;
            const int rem = idx - c4 * UNITS_PER_C4;
            const int row = rem / 17;
            const int u   = rem - row * 17;
            #pragma unroll
            for (int p = 0; p < 2; ++p) {
                const int pp = 2 * u + p;
                const unsigned int lo  = (unsigned int)f2bf(vals[k][0][p]) |
                                         ((unsigned int)f2bf(vals[k][1][p]) << 16);
                const unsigned int hi2 = (unsigned int)f2bf(vals[k][2][p]) |
                                         ((unsigned int)f2bf(vals[k][3][p]) << 16);
                const int s16 = ((c4 >> 1) ^ (pp >> 2) ^ (pp >> 3)) & 1;
                const int off = row * ROW_BYTES + pp * 32 + s16 * 16 + (c4 & 1) * 8;
                uint2v t; t.x = lo; t.y = hi2;
                *(uint2v*)(s_x + off) = t;
            }
        }
    }
    // same-wave ds_write -> ds_read ordering handled by lgkmcnt; no barrier.

    // ---- 2 output rows x 9 MFMAs; D col = pixel, D row(q) = outch ----
    #pragma unroll
    for (int t = 0; t < 2; ++t) {
        f32x16 acc;
        #pragma unroll
        for (int q = 0; q < 16; ++q) acc[q] = 0.0f;

        #pragma unroll
        for (int r = 0; r < 3; ++r) {
            #pragma unroll
            for (int s = 0; s < 3; ++s) {
                const int w   = n + s;
                const int s16 = (hi ^ (w >> 2) ^ (w >> 3)) & 1;
                const int off = (t + r) * ROW_BYTES + w * 32 + s16 * 16;
                const short8 xfr = *(const short8*)(s_x + off);   // ds_read_b128
                acc = __builtin_amdgcn_mfma_f32_32x32x16_bf16(af[r][s], xfr, acc, 0, 0, 0);
            }
        }

        // coalesced epilogue: 32 lanes (n=0..31) cover one full 128-B line
        const int h = h0 + t;
        #pragma unroll
        for (int q = 0; q < 16; ++q) {
            const int o = (q & 3) + 8 * (q >> 2) + 4 * hi;
            __builtin_nontemporal_store(acc[q], out + (o << 20) + (h << 10) + (w0 + n));
        }
    }
}

extern "C" void kernel_launch(void* const* d_in, const int* in_sizes, int n_in,
                              void* d_out, int out_size, void* d_ws, size_t ws_size,
                              hipStream_t stream) {
    (void)in_sizes; (void)n_in; (void)d_ws; (void)ws_size; (void)out_size;
    const float* x    = (const float*)d_in[0];
    const float* kern = (const float*)d_in[1];
    float*       out  = (float*)d_out;
    gck3x3_mfma_kernel<<<16384, 64, 0, stream>>>(x, kern, out);
}